// Round 3
// baseline (243.807 us; speedup 1.0000x reference)
//
#include <hip/hip_runtime.h>
#include <hip/hip_bf16.h>

#define E_NUM 64
#define IN_SZ 512
#define OUT_SZ 512
#define N_TOK 131072
#define CAP 3072

#define BM 128
#define BN 256
#define BK 32
#define THREADS 512
#define RT_MAX 24   // CAP/BM
#define CT_NUM 2    // OUT/BN
#define JT 16       // IN_SZ/BK

typedef __attribute__((ext_vector_type(8))) short short8;
typedef __attribute__((ext_vector_type(4))) float f32x4;

__device__ inline unsigned short f2bf(float f) {
    unsigned int u = __float_as_uint(f);
    unsigned int r = (u + 0x7FFF + ((u >> 16) & 1)) >> 16;
    return (unsigned short)r;
}

#define GLOAD_LDS16(g, l)                                                     \
    __builtin_amdgcn_global_load_lds(                                         \
        (const __attribute__((address_space(1))) void*)(g),                   \
        (__attribute__((address_space(3))) void*)(l), 16, 0, 0)

// ---------------- kernel 1: exclusive prefix sum of expert sizes ----------
__global__ void offsets_kernel(const int* __restrict__ sizes, int* __restrict__ offs) {
    int e = threadIdx.x;
    int s = 0;
    for (int i = 0; i < e; ++i) s += sizes[i];
    offs[e] = s;
}

// ---------------- kernel 2: W [E][K][N] f32 -> WT [E][N][K] bf16 ----------
__global__ __launch_bounds__(256) void prep_wt(const float* __restrict__ W,
                                               unsigned short* __restrict__ WT) {
    __shared__ float t[32][33];
    int k0 = blockIdx.x * 32, n0 = blockIdx.y * 32, e = blockIdx.z;
    const float* We = W + (size_t)e * IN_SZ * OUT_SZ;
    int tid = threadIdx.x;
    int r = tid >> 3, c4 = (tid & 7) * 4;
    float4 v = *(const float4*)(We + (size_t)(k0 + r) * OUT_SZ + n0 + c4);
    t[r][c4 + 0] = v.x; t[r][c4 + 1] = v.y; t[r][c4 + 2] = v.z; t[r][c4 + 3] = v.w;
    __syncthreads();
    ushort4 o;
    o.x = f2bf(t[c4 + 0][r]);
    o.y = f2bf(t[c4 + 1][r]);
    o.z = f2bf(t[c4 + 2][r]);
    o.w = f2bf(t[c4 + 3][r]);
    unsigned short* O = WT + (size_t)e * IN_SZ * OUT_SZ + (size_t)(n0 + r) * IN_SZ + k0 + c4;
    *(ushort4*)O = o;
}

// ---------------- kernel 3: grouped GEMM, 3-deep pipelined ----------------
// LDS swizzle (64B rows, 4 slots of 16B): chunk_byte ^= ((row&3)<<4).
// A: applied at ds_write and ds_read. B: global_load_lds writes linearly ->
// pre-swizzle GLOBAL source, same XOR on read (involution, rule #21).
// Pipeline: iter j computes tile j (buf j%3), ds_writes A(j+1) (buf (j+1)%3),
// stages B(j+2)+loads A(j+2) (buf (j+2)%3). s_waitcnt vmcnt(4) before the
// raw barrier drains B(j+1) collectively; B(j+2)/A(j+2) stay in flight.
__global__ __launch_bounds__(THREADS, 2) void gemm_moe(
    const float* __restrict__ A, const int* __restrict__ sizes,
    const unsigned short* __restrict__ WT, const int* __restrict__ offs,
    float* __restrict__ out)
{
    // bijective XCD swizzle: 3072 blocks, 384 per XCD chunk
    int b0 = blockIdx.x;
    int wg = (b0 & 7) * (E_NUM * RT_MAX * CT_NUM / 8) + (b0 >> 3);
    int ct = wg & (CT_NUM - 1);
    int rt = (wg >> 1) % RT_MAX;
    int e  = wg / (RT_MAX * CT_NUM);

    int size_e = sizes[e];
    int rows0 = rt * BM;
    if (rows0 >= size_e) return;
    int off_e = offs[e];
    int rows_rem = size_e - rows0;                      // >= 1
    int maxr = (rows_rem < BM ? rows_rem : BM) - 1;

    __shared__ unsigned short lsA[3][BM * BK];   // 3 x 8 KB
    __shared__ unsigned short lsB[3][BN * BK];   // 3 x 16 KB

    int tid = threadIdx.x, l = tid & 63, w = tid >> 6;
    const char* WTe = (const char*)(WT + (size_t)e * IN_SZ * OUT_SZ);
    const float* Abase = A + (size_t)(off_e + rows0) * IN_SZ;

    // A staging: unit = tid; row = tid>>2 (0..127), k-chunk = (tid&3)*8 f32
    int arow = tid >> 2;
    int garow = arow <= maxr ? arow : maxr;
    const float* aptr = Abase + (size_t)garow * IN_SZ + (tid & 3) * 8;
    int awaddr = arow * 64 + (((tid & 3) * 16) ^ ((arow & 3) << 4));

    // B staging: chunks c = w*2, w*2+1; lane source row = c*16 + (l>>2),
    // col = (l&3)*16 ^ (((l>>2)&3)<<4)  (lane-constant swizzle)
    int bsrc_col = ((l & 3) * 16) ^ (((l >> 2) & 3) << 4);
    int brow_l = l >> 2;

    float4 ar[2][2];   // two in-flight A register sets (static idx via unroll)

    auto loadA = [&](int kt, int p) {
        ar[p][0] = *(const float4*)(aptr + kt * BK);
        ar[p][1] = *(const float4*)(aptr + kt * BK + 4);
    };
    auto writeA = [&](int buf, int p) {
        short8 pk;
        pk[0] = (short)f2bf(ar[p][0].x); pk[1] = (short)f2bf(ar[p][0].y);
        pk[2] = (short)f2bf(ar[p][0].z); pk[3] = (short)f2bf(ar[p][0].w);
        pk[4] = (short)f2bf(ar[p][1].x); pk[5] = (short)f2bf(ar[p][1].y);
        pk[6] = (short)f2bf(ar[p][1].z); pk[7] = (short)f2bf(ar[p][1].w);
        *(short8*)((char*)&lsA[buf][0] + awaddr) = pk;
    };
    auto stageB = [&](int buf, int kt) {
        #pragma unroll
        for (int i = 0; i < 2; ++i) {
            int c = w * 2 + i;
            int row = c * 16 + brow_l;
            const char* g = WTe + (size_t)(ct * BN + row) * (IN_SZ * 2) + kt * 64 + bsrc_col;
            GLOAD_LDS16(g, &lsB[buf][c * 512]);
        }
    };

    int wm = (w >> 2) * 64, wn = (w & 3) * 64;
    int lrow = l & 15;
    int cb = ((l >> 4) * 16) ^ ((l & 3) << 4);

    f32x4 acc[4][4] = {};

    #define FRAGS_AND_MFMA(buf)                                               \
        {                                                                     \
            const char* pA = (const char*)&lsA[buf][0];                       \
            const char* pB = (const char*)&lsB[buf][0];                       \
            short8 af[4], bfr[4];                                             \
            _Pragma("unroll")                                                 \
            for (int m = 0; m < 4; ++m)                                       \
                af[m] = *(const short8*)(pA + (wm + m * 16 + lrow) * 64 + cb);\
            _Pragma("unroll")                                                 \
            for (int n = 0; n < 4; ++n)                                       \
                bfr[n] = *(const short8*)(pB + (wn + n * 16 + lrow) * 64 + cb);\
            asm volatile("s_waitcnt lgkmcnt(0)" ::: "memory");                \
            __builtin_amdgcn_sched_barrier(0);                                \
            __builtin_amdgcn_s_setprio(1);                                    \
            _Pragma("unroll")                                                 \
            for (int m = 0; m < 4; ++m)                                       \
                _Pragma("unroll")                                             \
                for (int n = 0; n < 4; ++n)                                   \
                    acc[m][n] = __builtin_amdgcn_mfma_f32_16x16x32_bf16(      \
                        af[m], bfr[n], acc[m][n], 0, 0, 0);                   \
            __builtin_amdgcn_s_setprio(0);                                    \
        }

    // ---- prologue: stage tiles 0 and 1 ----
    loadA(0, 0);
    stageB(0, 0);
    loadA(1, 1);
    stageB(1, 1);
    writeA(0, 0);                       // compiler waits its own vmcnt for ar[0]
    asm volatile("s_waitcnt vmcnt(4)" ::: "memory");   // B(0) landed
    __builtin_amdgcn_sched_barrier(0);
    asm volatile("s_waitcnt lgkmcnt(0)" ::: "memory"); // A(0) ds_write done
    __builtin_amdgcn_s_barrier();
    __builtin_amdgcn_sched_barrier(0);

    // ---- main loop: iters 0..13 (fully unrolled; all indices static) ----
    #pragma unroll
    for (int j = 0; j < JT - 2; ++j) {
        loadA(j + 2, j & 1);            // overwrites set consumed last iter
        stageB((j + 2) % 3, j + 2);
        writeA((j + 1) % 3, (j + 1) & 1);  // compiler inserts vmcnt for values
        FRAGS_AND_MFMA(j % 3);
        // drain B(j+1) before the barrier (cross-wave visibility);
        // A(j+2)/B(j+2) remain in flight across the barrier.
        asm volatile("s_waitcnt vmcnt(4)" ::: "memory");
        __builtin_amdgcn_sched_barrier(0);
        __builtin_amdgcn_s_barrier();
        __builtin_amdgcn_sched_barrier(0);
    }

    // ---- iter 14: no new stage; drain everything for tile 15 ----
    writeA((JT - 1) % 3, (JT - 1) & 1);
    FRAGS_AND_MFMA((JT - 2) % 3);
    asm volatile("s_waitcnt vmcnt(0)" ::: "memory");
    __builtin_amdgcn_sched_barrier(0);
    __builtin_amdgcn_s_barrier();
    __builtin_amdgcn_sched_barrier(0);

    // ---- iter 15: compute only ----
    FRAGS_AND_MFMA((JT - 1) % 3);

    // epilogue: C/D layout col = lane&15, row = (lane>>4)*4 + reg
    float* outb = out + (size_t)(off_e + rows0) * OUT_SZ + ct * BN + wn;
    #pragma unroll
    for (int m = 0; m < 4; ++m) {
        #pragma unroll
        for (int j = 0; j < 4; ++j) {
            int rl = wm + m * 16 + (l >> 4) * 4 + j;
            if (rl < rows_rem) {
                float* po = outb + (size_t)rl * OUT_SZ + lrow;
                #pragma unroll
                for (int n = 0; n < 4; ++n)
                    po[n * 16] = acc[m][n][j];
            }
        }
    }
}

extern "C" void kernel_launch(void* const* d_in, const int* in_sizes, int n_in,
                              void* d_out, int out_size, void* d_ws, size_t ws_size,
                              hipStream_t stream) {
    const float* A      = (const float*)d_in[0];
    const int* sizes    = (const int*)d_in[1];
    const float* W      = (const float*)d_in[2];
    float* out          = (float*)d_out;

    unsigned short* WT  = (unsigned short*)d_ws;                       // 32 MB
    int* offs           = (int*)((char*)d_ws + (size_t)E_NUM * IN_SZ * OUT_SZ * 2);

    offsets_kernel<<<1, E_NUM, 0, stream>>>(sizes, offs);
    prep_wt<<<dim3(IN_SZ / 32, OUT_SZ / 32, E_NUM), 256, 0, stream>>>(W, WT);
    gemm_moe<<<E_NUM * RT_MAX * CT_NUM, THREADS, 0, stream>>>(A, sizes, WT, offs, out);
}

// Round 4
// 190.785 us; speedup vs baseline: 1.2779x; 1.2779x over previous
//
#include <hip/hip_runtime.h>
#include <hip/hip_bf16.h>

#define E_NUM 64
#define IN_SZ 512
#define OUT_SZ 512
#define N_TOK 131072
#define CAP 3072

#define BM 128
#define BN 256
#define BK 32
#define THREADS 256
#define RT_MAX 24   // CAP/BM
#define CT_NUM 2    // OUT/BN
#define JT 16       // IN_SZ/BK

typedef __attribute__((ext_vector_type(8))) short short8;
typedef __attribute__((ext_vector_type(4))) float f32x4;

__device__ inline unsigned short f2bf(float f) {
    unsigned int u = __float_as_uint(f);
    unsigned int r = (u + 0x7FFF + ((u >> 16) & 1)) >> 16;
    return (unsigned short)r;
}

#define GLOAD_LDS16(g, l)                                                     \
    __builtin_amdgcn_global_load_lds(                                         \
        (const __attribute__((address_space(1))) void*)(g),                   \
        (__attribute__((address_space(3))) void*)(l), 16, 0, 0)

// ---------------- kernel 1: exclusive prefix sum of expert sizes ----------
__global__ void offsets_kernel(const int* __restrict__ sizes, int* __restrict__ offs) {
    int e = threadIdx.x;
    int s = 0;
    for (int i = 0; i < e; ++i) s += sizes[i];
    offs[e] = s;
}

// ---------------- kernel 2: W [E][K][N] f32 -> WT [E][N][K] bf16 ----------
__global__ __launch_bounds__(256) void prep_wt(const float* __restrict__ W,
                                               unsigned short* __restrict__ WT) {
    __shared__ float t[32][33];
    int k0 = blockIdx.x * 32, n0 = blockIdx.y * 32, e = blockIdx.z;
    const float* We = W + (size_t)e * IN_SZ * OUT_SZ;
    int tid = threadIdx.x;
    int r = tid >> 3, c4 = (tid & 7) * 4;
    float4 v = *(const float4*)(We + (size_t)(k0 + r) * OUT_SZ + n0 + c4);
    t[r][c4 + 0] = v.x; t[r][c4 + 1] = v.y; t[r][c4 + 2] = v.z; t[r][c4 + 3] = v.w;
    __syncthreads();
    ushort4 o;
    o.x = f2bf(t[c4 + 0][r]);
    o.y = f2bf(t[c4 + 1][r]);
    o.z = f2bf(t[c4 + 2][r]);
    o.w = f2bf(t[c4 + 3][r]);
    unsigned short* O = WT + (size_t)e * IN_SZ * OUT_SZ + (size_t)(n0 + r) * IN_SZ + k0 + c4;
    *(ushort4*)O = o;
}

// ---------------- kernel 3: grouped GEMM, 3-buffer counted-vmcnt ----------
// Swizzle (verified 0-conflict in R2): within each 64B k-row, 16B-slot index
// ^= (row>>1)&3.  A: applied at ds_write + ds_read.  B: global_load_lds
// writes linearly -> pre-swizzle GLOBAL source col, same XOR on read.
// Pipeline (3 LDS bufs, 2 A-reg sets):
//   iter j: loadA(j+2)->regs, stageB(j+2)->LDS(buf (j+2)%3)  [async]
//           MFMA on buf j%3
//           writeA(j+1) (cvt+ds_write; implicit vmcnt waits A(j+1), ~1.7 iters old)
//           s_waitcnt vmcnt(8)  -> B(j+1) landed; A(j+2)+B(j+2) stay in flight
//           s_waitcnt lgkmcnt(0) -> A(j+1) ds_writes visible; s_barrier
__global__ __launch_bounds__(THREADS, 2) void gemm_moe(
    const float* __restrict__ A, const int* __restrict__ sizes,
    const unsigned short* __restrict__ WT, const int* __restrict__ offs,
    float* __restrict__ out)
{
    // bijective XCD swizzle: 3072 blocks, 384 per XCD chunk
    int b0 = blockIdx.x;
    int wg = (b0 & 7) * (E_NUM * RT_MAX * CT_NUM / 8) + (b0 >> 3);
    int ct = wg & (CT_NUM - 1);
    int rt = (wg >> 1) % RT_MAX;
    int e  = wg / (RT_MAX * CT_NUM);

    int size_e = sizes[e];
    int rows0 = rt * BM;
    if (rows0 >= size_e) return;
    int off_e = offs[e];
    int rows_rem = size_e - rows0;                      // >= 1
    int maxr = (rows_rem < BM ? rows_rem : BM) - 1;

    __shared__ unsigned short lsA[3][BM * BK];   // 3 x 8 KB
    __shared__ unsigned short lsB[3][BN * BK];   // 3 x 16 KB

    int tid = threadIdx.x, l = tid & 63, w = tid >> 6;
    const char* WTe = (const char*)(WT + (size_t)e * IN_SZ * OUT_SZ);
    const float* Abase = A + (size_t)(off_e + rows0) * IN_SZ;

    // ---- A staging geometry (per i: idx = tid + 256*i) ----
    const float* ap[4];    // global row base + f32-quad offset
    int aw[4];             // swizzled LDS byte address
    #pragma unroll
    for (int i = 0; i < 4; ++i) {
        int idx = tid + THREADS * i;
        int row = idx >> 3, c4 = idx & 7;
        int gr = row <= maxr ? row : maxr;
        ap[i] = Abase + (size_t)gr * IN_SZ + c4 * 4;
        aw[i] = row * 64 + ((c4 * 8) ^ (((row >> 1) & 3) << 4));
    }
    // ---- B staging geometry (chunks c = w*4+i; LDS row = c*16 + l>>2) ----
    const char* gB[4];
    #pragma unroll
    for (int i = 0; i < 4; ++i) {
        int c = w * 4 + i;
        int n = c * 16 + (l >> 2);
        int csrc = ((l & 3) * 16) ^ (((l >> 3) & 3) << 4);
        gB[i] = WTe + (size_t)(ct * BN + n) * (IN_SZ * 2) + csrc;
    }

    float4 ar[2][4];   // 2 in-flight A register sets

    auto loadA = [&](int kt, int p) {
        #pragma unroll
        for (int i = 0; i < 4; ++i)
            ar[p][i] = *(const float4*)(ap[i] + kt * BK);
    };
    auto writeA = [&](int buf, int p) {
        #pragma unroll
        for (int i = 0; i < 4; ++i) {
            ushort4 pk;
            pk.x = f2bf(ar[p][i].x); pk.y = f2bf(ar[p][i].y);
            pk.z = f2bf(ar[p][i].z); pk.w = f2bf(ar[p][i].w);
            *(ushort4*)((char*)&lsA[buf][0] + aw[i]) = pk;
        }
    };
    auto stageB = [&](int buf, int kt) {
        #pragma unroll
        for (int i = 0; i < 4; ++i)
            GLOAD_LDS16(gB[i] + kt * 64, &lsB[buf][(w * 4 + i) * 512]);
    };

    int wm = (w >> 1) * 64, wn = (w & 1) * 128;
    int lrow = l & 15;
    int cb = ((l >> 4) * 16) ^ (((l >> 1) & 3) << 4);

    f32x4 acc[4][8] = {};

    #define FRAGS_AND_MFMA(buf)                                               \
        {                                                                     \
            const char* pA = (const char*)&lsA[buf][0];                       \
            const char* pB = (const char*)&lsB[buf][0];                       \
            short8 af[4];                                                     \
            _Pragma("unroll")                                                 \
            for (int m = 0; m < 4; ++m)                                       \
                af[m] = *(const short8*)(pA + (wm + m * 16 + lrow) * 64 + cb);\
            short8 bfr[8];                                                    \
            _Pragma("unroll")                                                 \
            for (int n = 0; n < 8; ++n)                                       \
                bfr[n] = *(const short8*)(pB + (wn + n * 16 + lrow) * 64 + cb);\
            asm volatile("s_waitcnt lgkmcnt(0)" ::: "memory");                \
            __builtin_amdgcn_sched_barrier(0);                                \
            __builtin_amdgcn_s_setprio(1);                                    \
            _Pragma("unroll")                                                 \
            for (int m = 0; m < 4; ++m)                                       \
                _Pragma("unroll")                                             \
                for (int n = 0; n < 8; ++n)                                   \
                    acc[m][n] = __builtin_amdgcn_mfma_f32_16x16x32_bf16(      \
                        af[m], bfr[n], acc[m][n], 0, 0, 0);                   \
            __builtin_amdgcn_s_setprio(0);                                    \
        }

    // ---- prologue: tiles 0,1 staged; A0 written ----
    loadA(0, 0); stageB(0, 0);
    loadA(1, 1); stageB(1, 1);
    writeA(0, 0);                                   // implicit wait on A0 loads
    asm volatile("s_waitcnt vmcnt(8)" ::: "memory");   // B0 landed; A1,B1 fly
    __builtin_amdgcn_sched_barrier(0);
    asm volatile("s_waitcnt lgkmcnt(0)" ::: "memory"); // A0 ds_writes visible
    __builtin_amdgcn_sched_barrier(0);
    __builtin_amdgcn_s_barrier();
    __builtin_amdgcn_sched_barrier(0);

    // ---- main loop, fully unrolled (all buf/set indices static) ----
    #pragma unroll
    for (int j = 0; j < JT; ++j) {
        if (j + 2 < JT) {
            loadA(j + 2, (j + 2) & 1);
            stageB((j + 2) % 3, j + 2);
        }
        FRAGS_AND_MFMA(j % 3);
        if (j + 1 < JT)
            writeA((j + 1) % 3, (j + 1) & 1);
        if (j < JT - 1) {
            if (j < JT - 2) {
                asm volatile("s_waitcnt vmcnt(8)" ::: "memory");
            } else {
                asm volatile("s_waitcnt vmcnt(0)" ::: "memory");
            }
            __builtin_amdgcn_sched_barrier(0);
            asm volatile("s_waitcnt lgkmcnt(0)" ::: "memory");
            __builtin_amdgcn_sched_barrier(0);
            __builtin_amdgcn_s_barrier();
            __builtin_amdgcn_sched_barrier(0);
        }
    }

    // epilogue: C/D layout col = lane&15, row = (lane>>4)*4 + reg
    float* outb = out + (size_t)(off_e + rows0) * OUT_SZ + ct * BN + wn;
    #pragma unroll
    for (int m = 0; m < 4; ++m) {
        #pragma unroll
        for (int j = 0; j < 4; ++j) {
            int rl = wm + m * 16 + (l >> 4) * 4 + j;
            if (rl < rows_rem) {
                float* po = outb + (size_t)rl * OUT_SZ + lrow;
                #pragma unroll
                for (int n = 0; n < 8; ++n)
                    po[n * 16] = acc[m][n][j];
            }
        }
    }
}

extern "C" void kernel_launch(void* const* d_in, const int* in_sizes, int n_in,
                              void* d_out, int out_size, void* d_ws, size_t ws_size,
                              hipStream_t stream) {
    const float* A      = (const float*)d_in[0];
    const int* sizes    = (const int*)d_in[1];
    const float* W      = (const float*)d_in[2];
    float* out          = (float*)d_out;

    unsigned short* WT  = (unsigned short*)d_ws;                       // 32 MB
    int* offs           = (int*)((char*)d_ws + (size_t)E_NUM * IN_SZ * OUT_SZ * 2);

    offsets_kernel<<<1, E_NUM, 0, stream>>>(sizes, offs);
    prep_wt<<<dim3(IN_SZ / 32, OUT_SZ / 32, E_NUM), 256, 0, stream>>>(W, WT);
    gemm_moe<<<E_NUM * RT_MAX * CT_NUM, THREADS, 0, stream>>>(A, sizes, WT, offs, out);
}